// Round 3
// baseline (222.000 us; speedup 1.0000x reference)
//
#include <hip/hip_runtime.h>
#include <stdint.h>

typedef unsigned short u16;
typedef unsigned int u32;
typedef __attribute__((ext_vector_type(4))) float floatx4;
typedef __attribute__((ext_vector_type(8))) short short8;

static __device__ __forceinline__ float bfhi2f(u32 hi) {
    union { u32 i; float f; } v; v.i = hi; return v.f;
}
static __device__ __forceinline__ u16 f2bf(float f) {
    union { float f; u32 i; } v; v.f = f;
    u32 r = v.i + 0x7fffu + ((v.i >> 16) & 1u);
    return (u16)(r >> 16);
}
static __device__ __forceinline__ float bf2f(u16 u) {
    union { u32 i; float f; } v; v.i = ((u32)u) << 16; return v.f;
}
static __device__ __forceinline__ uint4 pack8(const float* s) {
    float4 a = *(const float4*)s, b = *(const float4*)(s + 4);
    uint4 p;
    p.x = (u32)f2bf(a.x) | ((u32)f2bf(a.y) << 16);
    p.y = (u32)f2bf(a.z) | ((u32)f2bf(a.w) << 16);
    p.z = (u32)f2bf(b.x) | ((u32)f2bf(b.y) << 16);
    p.w = (u32)f2bf(b.z) | ((u32)f2bf(b.w) << 16);
    return p;
}

// ---------------- dtype detection ----------------
// flags[0] = 1 if float arrays are fp32 (else bf16)
// flags[1] = 1 if edge_index is int64 (else int32)

__global__ void detect_kernel(const u32* __restrict__ xw, const u32* __restrict__ eiw,
                              int* __restrict__ flags) {
    __shared__ int cnt_f32, cnt_zero;
    if (threadIdx.x == 0) { cnt_f32 = 0; cnt_zero = 0; }
    __syncthreads();
    int t = threadIdx.x;  // 256 threads
    u32 wx = xw[t];
    u32 e = (wx >> 23) & 0xffu;          // fp32 exponent field
    if (e >= 64 && e <= 191) atomicAdd(&cnt_f32, 1);   // N(0,1) fp32 always here; bf16-pairs never
    if (eiw[2 * t + 1] == 0) atomicAdd(&cnt_zero, 1);  // int64 high words are 0
    __syncthreads();
    if (t == 0) {
        flags[0] = (cnt_f32 >= 200) ? 1 : 0;
        flags[1] = (cnt_zero >= 250) ? 1 : 0;
    }
}

static __device__ __forceinline__ int load_row(const int* ei, int E, int e, int i64) {
    return i64 ? ei[2 * e] : ei[e];
}
static __device__ __forceinline__ int load_col(const int* ei, int E, int e, int i64) {
    return i64 ? ei[2 * E + 2 * e] : ei[E + e];
}

// ---------------- CSR build ----------------

__global__ void count_kernel(const int* __restrict__ ei, int E, int N,
                             const int* __restrict__ flags, int* __restrict__ counts) {
    int e = blockIdx.x * blockDim.x + threadIdx.x;
    if (e >= E) return;
    int i64 = flags[1];
    unsigned r = (unsigned)load_row(ei, E, e, i64);
    unsigned c = (unsigned)load_col(ei, E, e, i64);
    if (r < (unsigned)N && c < (unsigned)N) atomicAdd(&counts[r], 1);
}

__global__ void scan_kernel(const int* __restrict__ counts, int* __restrict__ offsets,
                            int* __restrict__ cursor, int n) {
    __shared__ int buf[1024];
    __shared__ int carry;
    int tid = threadIdx.x;
    if (tid == 0) carry = 0;
    __syncthreads();
    for (int base = 0; base < n; base += 1024) {
        int i = base + tid;
        int v = (i < n) ? counts[i] : 0;
        buf[tid] = v;
        __syncthreads();
        for (int d = 1; d < 1024; d <<= 1) {
            int t = (tid >= d) ? buf[tid - d] : 0;
            __syncthreads();
            buf[tid] += t;
            __syncthreads();
        }
        int incl = buf[tid] + carry;
        int excl = incl - v;
        if (i < n) { offsets[i] = excl; cursor[i] = excl; }
        __syncthreads();
        if (tid == 1023) carry = incl;
        __syncthreads();
    }
    if (tid == 0) offsets[n] = carry;
}

__global__ void fill_kernel(const int* __restrict__ ei, int E, int N,
                            const int* __restrict__ flags,
                            int* __restrict__ cursor, int* __restrict__ edge_dst) {
    int e = blockIdx.x * blockDim.x + threadIdx.x;
    if (e >= E) return;
    int i64 = flags[1];
    unsigned r = (unsigned)load_row(ei, E, e, i64);
    unsigned c = (unsigned)load_col(ei, E, e, i64);
    if (r < (unsigned)N && c < (unsigned)N) {
        int p = atomicAdd(&cursor[r], 1);
        edge_dst[p] = (int)c;
    }
}

// ---------------- aggregate: agg[n,0:512] (bf16) = sum over in-edges of x[col] ----------------

__global__ __launch_bounds__(256) void gather_kernel(
        const void* __restrict__ xin, const int* __restrict__ offsets,
        const int* __restrict__ edge_dst, const int* __restrict__ flags,
        u16* __restrict__ agg, int N) {
    int gw   = (blockIdx.x * 256 + threadIdx.x) >> 6;   // one wave per node
    int lane = threadIdx.x & 63;
    if (gw >= N) return;
    int f32 = flags[0];
    int beg = offsets[gw], end = offsets[gw + 1];
    float acc[8] = {0.f,0.f,0.f,0.f,0.f,0.f,0.f,0.f};
    const size_t lo = (size_t)lane * 8;
    if (f32) {
        const float* xf = (const float*)xin;
        for (int e = beg; e < end; ++e) {
            unsigned c = (unsigned)edge_dst[e];
            if (c >= (unsigned)N) continue;
            const float* s = xf + (size_t)c * 512 + lo;
            float4 a = *(const float4*)s, b = *(const float4*)(s + 4);
            acc[0] += a.x; acc[1] += a.y; acc[2] += a.z; acc[3] += a.w;
            acc[4] += b.x; acc[5] += b.y; acc[6] += b.z; acc[7] += b.w;
        }
    } else {
        const u16* xb = (const u16*)xin;
        for (int e = beg; e < end; ++e) {
            unsigned c = (unsigned)edge_dst[e];
            if (c >= (unsigned)N) continue;
            uint4 d = *(const uint4*)(xb + (size_t)c * 512 + lo);
            acc[0] += bfhi2f(d.x << 16); acc[1] += bfhi2f(d.x & 0xffff0000u);
            acc[2] += bfhi2f(d.y << 16); acc[3] += bfhi2f(d.y & 0xffff0000u);
            acc[4] += bfhi2f(d.z << 16); acc[5] += bfhi2f(d.z & 0xffff0000u);
            acc[6] += bfhi2f(d.w << 16); acc[7] += bfhi2f(d.w & 0xffff0000u);
        }
    }
    uint4 p;
    p.x = (u32)f2bf(acc[0]) | ((u32)f2bf(acc[1]) << 16);
    p.y = (u32)f2bf(acc[2]) | ((u32)f2bf(acc[3]) << 16);
    p.z = (u32)f2bf(acc[4]) | ((u32)f2bf(acc[5]) << 16);
    p.w = (u32)f2bf(acc[6]) | ((u32)f2bf(acc[7]) << 16);
    *(uint4*)(agg + (size_t)gw * 512 + lo) = p;
}

// ---------------- fused output GEMM ----------------
// colUnit 0: out[:,0:128]  = x[:,0:128]@Ws_root^T + agg[:,0:128]@Ws_rel^T + b
// colUnit c: out[:,128+jt] = x[:,128:512]@Wv_root^T + agg[:,128:512]@Wv_rel^T

#define LP 72   // LDS pitch in bf16 elems (64 + 8 pad)

__global__ __launch_bounds__(256, 2) void gemm_kernel(
        const void* __restrict__ xin, const u16* __restrict__ agg,
        const void* __restrict__ Ws_root, const void* __restrict__ Ws_rel,
        const void* __restrict__ bias,
        const void* __restrict__ Wv_root, const void* __restrict__ Wv_rel,
        const int* __restrict__ flags,
        void* __restrict__ outv, int N) {
    const int rowTile = blockIdx.x;
    const int colUnit = blockIdx.y;
    const bool is_scalar = (colUnit == 0);
    const int f32 = flags[0];
    const int K       = is_scalar ? 256 : 768;
    const int Kw      = is_scalar ? 128 : 384;
    const int selfOff = is_scalar ? 0   : 128;
    const void* Wroot = is_scalar ? Ws_root : Wv_root;
    const void* Wrel  = is_scalar ? Ws_rel  : Wv_rel;
    const int j0      = is_scalar ? 0 : (colUnit - 1) * 128;
    const int outOff  = is_scalar ? 0 : 128;

    __shared__ u16 As[128 * LP];
    __shared__ u16 Bs[128 * LP];

    const int row0 = rowTile * 128;
    const int tid  = threadIdx.x;
    const int lane = tid & 63, wid = tid >> 6;
    const int mBase = (wid >> 1) * 64, nBase = (wid & 1) * 64;
    const int lrow = lane & 15;
    const int lchunk = (lane >> 4) * 8;

    floatx4 acc[4][4];
#pragma unroll
    for (int i = 0; i < 4; ++i)
#pragma unroll
        for (int j = 0; j < 4; ++j) acc[i][j] = (floatx4){0.f, 0.f, 0.f, 0.f};

    for (int k0 = 0; k0 < K; k0 += 64) {
        const bool selfPhase = (k0 < Kw);
        const int acol = selfOff + (selfPhase ? k0 : (k0 - Kw));
#pragma unroll
        for (int it = 0; it < 4; ++it) {
            int c = it * 256 + tid;
            int r = c >> 3, cc = (c & 7) << 3;
            int ar = row0 + r; if (ar >= N) ar = N - 1;
            uint4 v;
            if (selfPhase) {
                if (f32) v = pack8((const float*)xin + (size_t)ar * 512 + acol + cc);
                else     v = *(const uint4*)((const u16*)xin + (size_t)ar * 512 + acol + cc);
            } else {
                v = *(const uint4*)(agg + (size_t)ar * 512 + acol + cc);
            }
            *(uint4*)&As[r * LP + cc] = v;
        }
        const void* Wsrc = selfPhase ? Wroot : Wrel;
        const int ks     = selfPhase ? k0 : (k0 - Kw);
#pragma unroll
        for (int it = 0; it < 4; ++it) {
            int c = it * 256 + tid;
            int r = c >> 3, cc = (c & 7) << 3;
            uint4 v;
            if (f32) v = pack8((const float*)Wsrc + (size_t)(j0 + r) * Kw + ks + cc);
            else     v = *(const uint4*)((const u16*)Wsrc + (size_t)(j0 + r) * Kw + ks + cc);
            *(uint4*)&Bs[r * LP + cc] = v;
        }
        __syncthreads();
#pragma unroll
        for (int kk = 0; kk < 64; kk += 32) {
            short8 a[4], b[4];
#pragma unroll
            for (int i = 0; i < 4; ++i)
                a[i] = *(const short8*)&As[(mBase + i * 16 + lrow) * LP + kk + lchunk];
#pragma unroll
            for (int j = 0; j < 4; ++j)
                b[j] = *(const short8*)&Bs[(nBase + j * 16 + lrow) * LP + kk + lchunk];
#pragma unroll
            for (int i = 0; i < 4; ++i)
#pragma unroll
                for (int j = 0; j < 4; ++j)
                    acc[i][j] = __builtin_amdgcn_mfma_f32_16x16x32_bf16(a[i], b[j], acc[i][j], 0, 0, 0);
        }
        __syncthreads();
    }

    // epilogue: C/D layout col=lane&15, row=(lane>>4)*4+reg
    const int lcol = lane & 15;
    const int lrow4 = (lane >> 4) * 4;
#pragma unroll
    for (int i = 0; i < 4; ++i) {
#pragma unroll
        for (int j = 0; j < 4; ++j) {
            int col = nBase + j * 16 + lcol;
            float bv = 0.f;
            if (is_scalar) bv = f32 ? ((const float*)bias)[col] : bf2f(((const u16*)bias)[col]);
#pragma unroll
            for (int r = 0; r < 4; ++r) {
                int row = row0 + mBase + i * 16 + lrow4 + r;
                if (row < N) {
                    size_t oi = (size_t)row * 512 + outOff + j0 + col;
                    float val = acc[i][j][r] + bv;
                    if (f32) ((float*)outv)[oi] = val;
                    else     ((u16*)outv)[oi]  = f2bf(val);
                }
            }
        }
    }
}

extern "C" void kernel_launch(void* const* d_in, const int* in_sizes, int n_in,
                              void* d_out, int out_size, void* d_ws, size_t ws_size,
                              hipStream_t stream) {
    const void* x      = d_in[0];
    const int* ei      = (const int*)d_in[1];
    const void* Wsrel  = d_in[2];
    const void* Wsroot = d_in[3];
    const void* bs     = d_in[4];
    const void* Wvrel  = d_in[5];
    const void* Wvroot = d_in[6];

    const int N = in_sizes[0] / 512;
    const int E = in_sizes[1] / 2;
    const int Mtiles = (N + 127) / 128;

    // ws layout (~11.2 MB): flags + CSR arrays first, agg last
    char* ws = (char*)d_ws;
    size_t off = 0;
    int* flags = (int*)(ws + off);   off += 256;
    int* counts = (int*)(ws + off);  off += (size_t)N * 4;       off = (off + 255) & ~(size_t)255;
    int* offsets = (int*)(ws + off); off += (size_t)(N + 1) * 4; off = (off + 255) & ~(size_t)255;
    int* cursor = (int*)(ws + off);  off += (size_t)N * 4;       off = (off + 255) & ~(size_t)255;
    int* edge_dst = (int*)(ws + off); off += (size_t)E * 4;      off = (off + 255) & ~(size_t)255;
    u16* agg = (u16*)(ws + off);

    hipMemsetAsync(counts, 0, (size_t)N * 4, stream);
    detect_kernel<<<1, 256, 0, stream>>>((const u32*)x, (const u32*)ei, flags);
    count_kernel<<<(E + 255) / 256, 256, 0, stream>>>(ei, E, N, flags, counts);
    scan_kernel<<<1, 1024, 0, stream>>>(counts, offsets, cursor, N);
    fill_kernel<<<(E + 255) / 256, 256, 0, stream>>>(ei, E, N, flags, cursor, edge_dst);
    gather_kernel<<<(N * 64 + 255) / 256, 256, 0, stream>>>(x, offsets, edge_dst, flags, agg, N);
    dim3 grid(Mtiles, 4);
    gemm_kernel<<<grid, 256, 0, stream>>>(x, agg, Wsroot, Wsrel, bs, Wvroot, Wvrel, flags, d_out, N);
}

// Round 4
// 176.527 us; speedup vs baseline: 1.2576x; 1.2576x over previous
//
#include <hip/hip_runtime.h>
#include <stdint.h>

typedef unsigned short u16;
typedef unsigned int u32;
typedef __attribute__((ext_vector_type(4))) float floatx4;
typedef __attribute__((ext_vector_type(8))) short short8;

static __device__ __forceinline__ float bfhi2f(u32 hi) {
    union { u32 i; float f; } v; v.i = hi; return v.f;
}
static __device__ __forceinline__ u16 f2bf(float f) {
    union { float f; u32 i; } v; v.f = f;
    u32 r = v.i + 0x7fffu + ((v.i >> 16) & 1u);
    return (u16)(r >> 16);
}
static __device__ __forceinline__ float bf2f(u16 u) {
    union { u32 i; float f; } v; v.i = ((u32)u) << 16; return v.f;
}
static __device__ __forceinline__ uint4 pack8(const float* s) {
    float4 a = *(const float4*)s, b = *(const float4*)(s + 4);
    uint4 p;
    p.x = (u32)f2bf(a.x) | ((u32)f2bf(a.y) << 16);
    p.y = (u32)f2bf(a.z) | ((u32)f2bf(a.w) << 16);
    p.z = (u32)f2bf(b.x) | ((u32)f2bf(b.y) << 16);
    p.w = (u32)f2bf(b.z) | ((u32)f2bf(b.w) << 16);
    return p;
}

// ---------------- dtype detection ----------------
// flags[0]=1 if float arrays are fp32 (else bf16); flags[1]=1 if edge_index is int64

__global__ void detect_kernel(const u32* __restrict__ xw, const u32* __restrict__ eiw,
                              int* __restrict__ flags) {
    __shared__ int cnt_f32, cnt_zero;
    if (threadIdx.x == 0) { cnt_f32 = 0; cnt_zero = 0; }
    __syncthreads();
    int t = threadIdx.x;  // 256 threads
    u32 wx = xw[t];
    u32 e = (wx >> 23) & 0xffu;
    if (e >= 64 && e <= 191) atomicAdd(&cnt_f32, 1);
    if (eiw[2 * t + 1] == 0) atomicAdd(&cnt_zero, 1);
    __syncthreads();
    if (t == 0) {
        flags[0] = (cnt_f32 >= 200) ? 1 : 0;
        flags[1] = (cnt_zero >= 250) ? 1 : 0;
    }
}

// ---------------- bf16 conversion ----------------

__global__ __launch_bounds__(256) void convert_x_kernel(
        const float* __restrict__ x, u16* __restrict__ xb, int n8,
        const int* __restrict__ flags) {
    if (!flags[0]) return;                 // input already bf16; xb unused
    int t = blockIdx.x * 256 + threadIdx.x;
    if (t >= n8) return;
    *(uint4*)(xb + (size_t)t * 8) = pack8(x + (size_t)t * 8);
}

// Wb layout: [Wsrel(s2) | Wsroot(s2) | Wvrel(s5) | Wvroot(s5)]
__global__ __launch_bounds__(256) void convert_w_kernel(
        const void* __restrict__ w2, const void* __restrict__ w3,
        const void* __restrict__ w5, const void* __restrict__ w6,
        u16* __restrict__ out, int s2, int s5, const int* __restrict__ flags) {
    int f32 = flags[0];
    int t = blockIdx.x * 256 + threadIdx.x;
    int g = t * 8;
    int total = 2 * s2 + 2 * s5;
    if (g >= total) return;
    const void* src; int loc;
    if (g < s2)            { src = w2; loc = g; }
    else if (g < 2*s2)     { src = w3; loc = g - s2; }
    else if (g < 2*s2+s5)  { src = w5; loc = g - 2*s2; }
    else                   { src = w6; loc = g - 2*s2 - s5; }
    uint4 v;
    if (f32) v = pack8((const float*)src + loc);
    else     v = *(const uint4*)((const u16*)src + loc);
    *(uint4*)(out + g) = v;
}

// ---------------- CSR build ----------------

static __device__ __forceinline__ int load_row(const int* ei, int E, int e, int i64) {
    return i64 ? ei[2 * e] : ei[e];
}
static __device__ __forceinline__ int load_col(const int* ei, int E, int e, int i64) {
    return i64 ? ei[2 * E + 2 * e] : ei[E + e];
}

__global__ void count_kernel(const int* __restrict__ ei, int E, int N,
                             const int* __restrict__ flags, int* __restrict__ counts) {
    int e = blockIdx.x * blockDim.x + threadIdx.x;
    if (e >= E) return;
    int i64 = flags[1];
    unsigned r = (unsigned)load_row(ei, E, e, i64);
    unsigned c = (unsigned)load_col(ei, E, e, i64);
    if (r < (unsigned)N && c < (unsigned)N) atomicAdd(&counts[r], 1);
}

// 1024-thread single block, wave-shuffle scan (2 barriers per 1024-chunk)
__global__ void scan_kernel(const int* __restrict__ counts, int* __restrict__ offsets,
                            int* __restrict__ cursor, int n) {
    __shared__ int part[16];
    __shared__ int carry;
    const int tid = threadIdx.x, lane = tid & 63, wave = tid >> 6;
    if (tid == 0) carry = 0;
    __syncthreads();
    for (int base = 0; base < n; base += 1024) {
        int i = base + tid;
        int v = (i < n) ? counts[i] : 0;
        int s = v;
#pragma unroll
        for (int d = 1; d < 64; d <<= 1) {
            int t = __shfl_up(s, d);
            if (lane >= d) s += t;
        }
        if (lane == 63) part[wave] = s;
        __syncthreads();                       // A
        if (tid < 16) {
            int p = part[tid];
#pragma unroll
            for (int d = 1; d < 16; d <<= 1) {
                int t = __shfl_up(p, d);
                if (tid >= d) p += t;
            }
            part[tid] = p;
        }
        __syncthreads();                       // B
        int c0 = carry;
        int woff = wave ? part[wave - 1] : 0;
        int excl = c0 + woff + s - v;
        if (i < n) { offsets[i] = excl; cursor[i] = excl; }
        int tot = part[15];
        __syncthreads();                       // C
        if (tid == 0) carry = c0 + tot;
    }
    __syncthreads();
    if (tid == 0) offsets[n] = carry;
}

__global__ void fill_kernel(const int* __restrict__ ei, int E, int N,
                            const int* __restrict__ flags,
                            int* __restrict__ cursor, int* __restrict__ edge_dst) {
    int e = blockIdx.x * blockDim.x + threadIdx.x;
    if (e >= E) return;
    int i64 = flags[1];
    unsigned r = (unsigned)load_row(ei, E, e, i64);
    unsigned c = (unsigned)load_col(ei, E, e, i64);
    if (r < (unsigned)N && c < (unsigned)N) {
        int p = atomicAdd(&cursor[r], 1);
        edge_dst[p] = (int)c;
    }
}

// ---------------- aggregate: agg[n,0:512] (bf16) = sum over in-edges ----------------

__global__ __launch_bounds__(256) void gather_kernel(
        const void* __restrict__ xin, const u16* __restrict__ x_bf,
        const int* __restrict__ offsets, const int* __restrict__ edge_dst,
        const int* __restrict__ flags, int use_xbf,
        u16* __restrict__ agg, int N) {
    int gw   = (blockIdx.x * 256 + threadIdx.x) >> 6;   // one wave per node
    int lane = threadIdx.x & 63;
    if (gw >= N) return;
    const int f32 = flags[0];
    const bool read_bf = use_xbf || !f32;
    const u16* xb = (f32 && use_xbf) ? x_bf : (const u16*)xin;
    int beg = offsets[gw], end = offsets[gw + 1];
    float acc[8] = {0.f,0.f,0.f,0.f,0.f,0.f,0.f,0.f};
    const size_t lo = (size_t)lane * 8;
    if (read_bf) {
        for (int e = beg; e < end; ++e) {
            unsigned c = (unsigned)edge_dst[e];
            if (c >= (unsigned)N) continue;
            uint4 d = *(const uint4*)(xb + (size_t)c * 512 + lo);
            acc[0] += bfhi2f(d.x << 16); acc[1] += bfhi2f(d.x & 0xffff0000u);
            acc[2] += bfhi2f(d.y << 16); acc[3] += bfhi2f(d.y & 0xffff0000u);
            acc[4] += bfhi2f(d.z << 16); acc[5] += bfhi2f(d.z & 0xffff0000u);
            acc[6] += bfhi2f(d.w << 16); acc[7] += bfhi2f(d.w & 0xffff0000u);
        }
    } else {
        const float* xf = (const float*)xin;
        for (int e = beg; e < end; ++e) {
            unsigned c = (unsigned)edge_dst[e];
            if (c >= (unsigned)N) continue;
            const float* s = xf + (size_t)c * 512 + lo;
            float4 a = *(const float4*)s, b = *(const float4*)(s + 4);
            acc[0] += a.x; acc[1] += a.y; acc[2] += a.z; acc[3] += a.w;
            acc[4] += b.x; acc[5] += b.y; acc[6] += b.z; acc[7] += b.w;
        }
    }
    uint4 p;
    p.x = (u32)f2bf(acc[0]) | ((u32)f2bf(acc[1]) << 16);
    p.y = (u32)f2bf(acc[2]) | ((u32)f2bf(acc[3]) << 16);
    p.z = (u32)f2bf(acc[4]) | ((u32)f2bf(acc[5]) << 16);
    p.w = (u32)f2bf(acc[6]) | ((u32)f2bf(acc[7]) << 16);
    *(uint4*)(agg + (size_t)gw * 512 + lo) = p;
}

// ---------------- fused output GEMM (64x64 tiles, grid Mt x 8) ----------------
// units 0-1: out[:, u*64 .. u*64+63]      = x[:,0:128]@Ws_root^T + agg@Ws_rel^T + b
// units 2-7: out[:, 128+(u-2)*64 .. +63]  = x[:,128:512]@Wv_root^T + agg@Wv_rel^T

#define LP 72   // LDS pitch in bf16 elems (64 + 8 pad)

__global__ __launch_bounds__(256, 4) void gemm_kernel(
        const void* __restrict__ xin, const u16* __restrict__ x_bf,
        const u16* __restrict__ agg, const u16* __restrict__ Wb,
        const void* __restrict__ bias, const int* __restrict__ flags,
        int use_xbf, int s2, int s5,
        void* __restrict__ outv, int N) {
    const int unit = blockIdx.y;
    const bool is_scalar = (unit < 2);
    const int f32 = flags[0];
    const bool read_bf = use_xbf || !f32;
    const u16* xb = (f32 && use_xbf) ? x_bf : (const u16*)xin;

    const int Kw      = is_scalar ? 128 : 384;
    const int K       = 2 * Kw;
    const int selfOff = is_scalar ? 0 : 128;
    const int j0      = is_scalar ? unit * 64 : (unit - 2) * 64;
    const int outOff  = is_scalar ? 0 : 128;
    const u16* Wrel   = is_scalar ? Wb : (Wb + 2 * s2);
    const u16* Wroot  = is_scalar ? (Wb + s2) : (Wb + 2 * s2 + s5);

    __shared__ u16 As[64 * LP];
    __shared__ u16 Bs[64 * LP];

    const int row0 = blockIdx.x * 64;
    const int tid  = threadIdx.x;
    const int lane = tid & 63, wid = tid >> 6;
    const int mBase = (wid >> 1) * 32, nBase = (wid & 1) * 32;
    const int lrow = lane & 15;
    const int lchunk = (lane >> 4) * 8;

    floatx4 acc[2][2];
#pragma unroll
    for (int i = 0; i < 2; ++i)
#pragma unroll
        for (int j = 0; j < 2; ++j) acc[i][j] = (floatx4){0.f, 0.f, 0.f, 0.f};

    for (int k0 = 0; k0 < K; k0 += 64) {
        const bool selfPhase = (k0 < Kw);
        const int acol = selfOff + (selfPhase ? k0 : (k0 - Kw));
        const int ks   = selfPhase ? k0 : (k0 - Kw);
        const u16* Wsrc = selfPhase ? Wroot : Wrel;
#pragma unroll
        for (int it = 0; it < 2; ++it) {
            int ci = it * 256 + tid;           // 0..511 chunk index
            int r = ci >> 3, cc = (ci & 7) << 3;
            int ar = row0 + r; if (ar >= N) ar = N - 1;
            uint4 va;
            if (selfPhase) {
                if (read_bf) va = *(const uint4*)(xb + (size_t)ar * 512 + acol + cc);
                else         va = pack8((const float*)xin + (size_t)ar * 512 + acol + cc);
            } else {
                va = *(const uint4*)(agg + (size_t)ar * 512 + acol + cc);
            }
            *(uint4*)&As[r * LP + cc] = va;
            *(uint4*)&Bs[r * LP + cc] =
                *(const uint4*)(Wsrc + (size_t)(j0 + r) * Kw + ks + cc);
        }
        __syncthreads();
#pragma unroll
        for (int kk = 0; kk < 64; kk += 32) {
            short8 a[2], b[2];
#pragma unroll
            for (int i = 0; i < 2; ++i)
                a[i] = *(const short8*)&As[(mBase + i * 16 + lrow) * LP + kk + lchunk];
#pragma unroll
            for (int j = 0; j < 2; ++j)
                b[j] = *(const short8*)&Bs[(nBase + j * 16 + lrow) * LP + kk + lchunk];
#pragma unroll
            for (int i = 0; i < 2; ++i)
#pragma unroll
                for (int j = 0; j < 2; ++j)
                    acc[i][j] = __builtin_amdgcn_mfma_f32_16x16x32_bf16(a[i], b[j], acc[i][j], 0, 0, 0);
        }
        __syncthreads();
    }

    // epilogue: C/D layout col=lane&15, row=(lane>>4)*4+reg
    const int lcol = lane & 15;
    const int lrow4 = (lane >> 4) * 4;
#pragma unroll
    for (int i = 0; i < 2; ++i) {
#pragma unroll
        for (int j = 0; j < 2; ++j) {
            int col = nBase + j * 16 + lcol;     // 0..63 within tile
            float bv = 0.f;
            if (is_scalar)
                bv = f32 ? ((const float*)bias)[j0 + col]
                         : bf2f(((const u16*)bias)[j0 + col]);
#pragma unroll
            for (int r = 0; r < 4; ++r) {
                int row = row0 + mBase + i * 16 + lrow4 + r;
                if (row < N) {
                    size_t oi = (size_t)row * 512 + outOff + j0 + col;
                    float val = acc[i][j][r] + bv;
                    if (f32) ((float*)outv)[oi] = val;
                    else     ((u16*)outv)[oi]  = f2bf(val);
                }
            }
        }
    }
}

extern "C" void kernel_launch(void* const* d_in, const int* in_sizes, int n_in,
                              void* d_out, int out_size, void* d_ws, size_t ws_size,
                              hipStream_t stream) {
    const void* x      = d_in[0];
    const int* ei      = (const int*)d_in[1];
    const void* Wsrel  = d_in[2];
    const void* Wsroot = d_in[3];
    const void* bs     = d_in[4];
    const void* Wvrel  = d_in[5];
    const void* Wvroot = d_in[6];

    const int N  = in_sizes[0] / 512;
    const int E  = in_sizes[1] / 2;
    const int s2 = in_sizes[2];          // scalar W elems (HIDDEN^2)
    const int s5 = in_sizes[5];          // vector W elems ((3H)^2)
    const int Nx = in_sizes[0];          // N*512
    const int Mt = (N + 63) / 64;

    // ws layout: small stuff first, agg, then optional x_bf (adaptive)
    char* ws = (char*)d_ws;
    size_t off = 0;
    int* flags = (int*)(ws + off);    off += 256;
    int* counts = (int*)(ws + off);   off += (size_t)N * 4;        off = (off + 255) & ~(size_t)255;
    int* offsets = (int*)(ws + off);  off += (size_t)(N + 1) * 4;  off = (off + 255) & ~(size_t)255;
    int* cursor = (int*)(ws + off);   off += (size_t)N * 4;        off = (off + 255) & ~(size_t)255;
    int* edge_dst = (int*)(ws + off); off += (size_t)E * 4;        off = (off + 255) & ~(size_t)255;
    u16* Wb = (u16*)(ws + off);       off += (size_t)(2*s2 + 2*s5) * 2; off = (off + 255) & ~(size_t)255;
    u16* agg = (u16*)(ws + off);      off += (size_t)Nx * 2;       off = (off + 255) & ~(size_t)255;
    u16* x_bf = (u16*)(ws + off);
    const size_t need_full = off + (size_t)Nx * 2;
    const int use_xbf = (ws_size >= need_full) ? 1 : 0;

    hipMemsetAsync(counts, 0, (size_t)N * 4, stream);
    detect_kernel<<<1, 256, 0, stream>>>((const u32*)x, (const u32*)ei, flags);
    if (use_xbf)
        convert_x_kernel<<<(Nx / 8 + 255) / 256, 256, 0, stream>>>(
            (const float*)x, x_bf, Nx / 8, flags);
    convert_w_kernel<<<((2*s2 + 2*s5) / 8 + 255) / 256, 256, 0, stream>>>(
        Wsrel, Wsroot, Wvrel, Wvroot, Wb, s2, s5, flags);
    count_kernel<<<(E + 255) / 256, 256, 0, stream>>>(ei, E, N, flags, counts);
    scan_kernel<<<1, 1024, 0, stream>>>(counts, offsets, cursor, N);
    fill_kernel<<<(E + 255) / 256, 256, 0, stream>>>(ei, E, N, flags, cursor, edge_dst);
    gather_kernel<<<(N * 64 + 255) / 256, 256, 0, stream>>>(
        x, x_bf, offsets, edge_dst, flags, use_xbf, agg, N);
    dim3 grid(Mt, 8);
    gemm_kernel<<<grid, 256, 0, stream>>>(
        x, x_bf, agg, Wb, bs, flags, use_xbf, s2, s5, d_out, N);
}

// Round 6
// 161.307 us; speedup vs baseline: 1.3763x; 1.0944x over previous
//
#include <hip/hip_runtime.h>
#include <stdint.h>

typedef unsigned short u16;
typedef unsigned int u32;
typedef __attribute__((ext_vector_type(4))) float floatx4;
typedef __attribute__((ext_vector_type(8))) short short8;

// Dtypes fixed by harness convention: float32 tensors (proved R3: fp32
// epilogue passed), edge_index int32 (harness: "integer -> const int*";
// R5's int64 read aborted with a page fault, R3/R4 passed on int32 path).

static __device__ __forceinline__ float bfhi2f(u32 hi) {
    union { u32 i; float f; } v; v.i = hi; return v.f;
}
static __device__ __forceinline__ u16 f2bf(float f) {
    union { float f; u32 i; } v; v.f = f;
    u32 r = v.i + 0x7fffu + ((v.i >> 16) & 1u);
    return (u16)(r >> 16);
}
static __device__ __forceinline__ uint4 pack8(const float* s) {
    float4 a = *(const float4*)s, b = *(const float4*)(s + 4);
    uint4 p;
    p.x = (u32)f2bf(a.x) | ((u32)f2bf(a.y) << 16);
    p.y = (u32)f2bf(a.z) | ((u32)f2bf(a.w) << 16);
    p.z = (u32)f2bf(b.x) | ((u32)f2bf(b.y) << 16);
    p.w = (u32)f2bf(b.z) | ((u32)f2bf(b.w) << 16);
    return p;
}

// ---------------- fused prep: x->bf16, W->bf16 (concat), edge count ----------------
// Wb layout: [Wsrel(s2) | Wsroot(s2) | Wvrel(s5) | Wvroot(s5)]

__global__ __launch_bounds__(256) void prep_kernel(
        const float* __restrict__ x, u16* __restrict__ xb, int n8,
        const float* __restrict__ w2, const float* __restrict__ w3,
        const float* __restrict__ w5, const float* __restrict__ w6,
        u16* __restrict__ Wb, int s2, int s5, int nw8,
        const int* __restrict__ ei, int E, int N, int* __restrict__ counts,
        int nb_x, int nb_w) {
    const int b = blockIdx.x, tid = threadIdx.x;
    if (b < nb_x) {
        int t = b * 256 + tid;
        if (t < n8) *(uint4*)(xb + (size_t)t * 8) = pack8(x + (size_t)t * 8);
    } else if (b < nb_x + nb_w) {
        int t = (b - nb_x) * 256 + tid;
        if (t < nw8) {
            int g = t * 8;
            const float* src; int loc;
            if (g < s2)               { src = w2; loc = g; }
            else if (g < 2 * s2)      { src = w3; loc = g - s2; }
            else if (g < 2 * s2 + s5) { src = w5; loc = g - 2 * s2; }
            else                      { src = w6; loc = g - 2 * s2 - s5; }
            *(uint4*)(Wb + g) = pack8(src + loc);
        }
    } else {
        int e = (b - nb_x - nb_w) * 256 + tid;
        if (e < E) {
            unsigned r = (unsigned)ei[e];
            unsigned c = (unsigned)ei[E + e];
            if (r < (unsigned)N && c < (unsigned)N) atomicAdd(&counts[r], 1);
        }
    }
}

// ---------------- single-block wave-shuffle scan ----------------

__global__ void scan_kernel(const int* __restrict__ counts, int* __restrict__ offsets,
                            int* __restrict__ cursor, int n) {
    __shared__ int part[16];
    __shared__ int carry;
    const int tid = threadIdx.x, lane = tid & 63, wave = tid >> 6;
    if (tid == 0) carry = 0;
    __syncthreads();
    for (int base = 0; base < n; base += 1024) {
        int i = base + tid;
        int v = (i < n) ? counts[i] : 0;
        int s = v;
#pragma unroll
        for (int d = 1; d < 64; d <<= 1) {
            int t = __shfl_up(s, d);
            if (lane >= d) s += t;
        }
        if (lane == 63) part[wave] = s;
        __syncthreads();
        if (tid < 16) {
            int p = part[tid];
#pragma unroll
            for (int d = 1; d < 16; d <<= 1) {
                int t = __shfl_up(p, d);
                if (tid >= d) p += t;
            }
            part[tid] = p;
        }
        __syncthreads();
        int c0 = carry;
        int woff = wave ? part[wave - 1] : 0;
        int excl = c0 + woff + s - v;
        if (i < n) { offsets[i] = excl; cursor[i] = excl; }
        int tot = part[15];
        __syncthreads();
        if (tid == 0) carry = c0 + tot;
    }
    __syncthreads();
    if (tid == 0) offsets[n] = carry;
}

__global__ void fill_kernel(const int* __restrict__ ei, int E, int N,
                            int* __restrict__ cursor, int* __restrict__ edge_dst) {
    int e = blockIdx.x * blockDim.x + threadIdx.x;
    if (e >= E) return;
    unsigned r = (unsigned)ei[e];
    unsigned c = (unsigned)ei[E + e];
    if (r < (unsigned)N && c < (unsigned)N) {
        int p = atomicAdd(&cursor[r], 1);
        edge_dst[p] = (int)c;
    }
}

// ---------------- aggregate: agg[n,0:512] (bf16) = sum over in-edges ----------------
// One wave per node; 8-deep explicit prefetch keeps 8 row-loads in flight.

static __device__ __forceinline__ void acc8(float* acc, uint4 d) {
    acc[0] += bfhi2f(d.x << 16); acc[1] += bfhi2f(d.x & 0xffff0000u);
    acc[2] += bfhi2f(d.y << 16); acc[3] += bfhi2f(d.y & 0xffff0000u);
    acc[4] += bfhi2f(d.z << 16); acc[5] += bfhi2f(d.z & 0xffff0000u);
    acc[6] += bfhi2f(d.w << 16); acc[7] += bfhi2f(d.w & 0xffff0000u);
}

__global__ __launch_bounds__(256) void gather_kernel(
        const u16* __restrict__ xb, const int* __restrict__ offsets,
        const int* __restrict__ edge_dst, u16* __restrict__ agg, int N) {
    int gw   = (blockIdx.x * 256 + threadIdx.x) >> 6;
    int lane = threadIdx.x & 63;
    if (gw >= N) return;
    const int beg = offsets[gw], end = offsets[gw + 1];
    float acc[8] = {0.f,0.f,0.f,0.f,0.f,0.f,0.f,0.f};
    const u16* xl = xb + (size_t)lane * 8;   // lane's 16B column slot
    int e = beg;
    for (; e + 8 <= end; e += 8) {
        int c[8];
#pragma unroll
        for (int u = 0; u < 8; ++u) c[u] = edge_dst[e + u];
        uint4 d[8];
#pragma unroll
        for (int u = 0; u < 8; ++u) d[u] = *(const uint4*)(xl + (size_t)c[u] * 512);
#pragma unroll
        for (int u = 0; u < 8; ++u) acc8(acc, d[u]);
    }
    for (; e < end; ++e) {
        int c = edge_dst[e];
        acc8(acc, *(const uint4*)(xl + (size_t)c * 512));
    }
    uint4 p;
    p.x = (u32)f2bf(acc[0]) | ((u32)f2bf(acc[1]) << 16);
    p.y = (u32)f2bf(acc[2]) | ((u32)f2bf(acc[3]) << 16);
    p.z = (u32)f2bf(acc[4]) | ((u32)f2bf(acc[5]) << 16);
    p.w = (u32)f2bf(acc[6]) | ((u32)f2bf(acc[7]) << 16);
    *(uint4*)(agg + (size_t)gw * 512 + (size_t)lane * 8) = p;
}

// ---------------- fused output GEMM (64x64 tiles, grid Mt x 8) ----------------
// units 0-1: out[:, u*64+0..63]          = x[:,0:128]@Ws_root^T + agg[:,0:128]@Ws_rel^T + b
// units 2-7: out[:, 128+(u-2)*64+0..63]  = x[:,128:512]@Wv_root^T + agg[:,128:512]@Wv_rel^T

#define LP 72   // LDS pitch in bf16 elems (64 + 8 pad)

__global__ __launch_bounds__(256, 4) void gemm_kernel(
        const u16* __restrict__ xb, const u16* __restrict__ agg,
        const u16* __restrict__ Wb, const float* __restrict__ bias,
        int s2, int s5, float* __restrict__ out, int N) {
    const int unit = blockIdx.y;
    const bool is_scalar = (unit < 2);

    const int Kw      = is_scalar ? 128 : 384;
    const int K       = 2 * Kw;
    const int selfOff = is_scalar ? 0 : 128;
    const int j0      = is_scalar ? unit * 64 : (unit - 2) * 64;
    const int outOff  = is_scalar ? 0 : 128;
    const u16* Wrel   = is_scalar ? Wb : (Wb + 2 * s2);
    const u16* Wroot  = is_scalar ? (Wb + s2) : (Wb + 2 * s2 + s5);

    __shared__ u16 As[64 * LP];
    __shared__ u16 Bs[64 * LP];

    const int row0 = blockIdx.x * 64;
    const int tid  = threadIdx.x;
    const int lane = tid & 63, wid = tid >> 6;
    const int mBase = (wid >> 1) * 32, nBase = (wid & 1) * 32;
    const int lrow = lane & 15;
    const int lchunk = (lane >> 4) * 8;

    floatx4 acc[2][2];
#pragma unroll
    for (int i = 0; i < 2; ++i)
#pragma unroll
        for (int j = 0; j < 2; ++j) acc[i][j] = (floatx4){0.f, 0.f, 0.f, 0.f};

    for (int k0 = 0; k0 < K; k0 += 64) {
        const bool selfPhase = (k0 < Kw);
        const int ks   = selfPhase ? k0 : (k0 - Kw);
        const int acol = selfOff + ks;
        const u16* Asrc = selfPhase ? xb : agg;
        const u16* Wsrc = selfPhase ? Wroot : Wrel;
#pragma unroll
        for (int it = 0; it < 2; ++it) {
            int ci = it * 256 + tid;            // 0..511 chunk index
            int r = ci >> 3, cc = (ci & 7) << 3;
            int ar = row0 + r; if (ar >= N) ar = N - 1;
            *(uint4*)&As[r * LP + cc] =
                *(const uint4*)(Asrc + (size_t)ar * 512 + acol + cc);
            *(uint4*)&Bs[r * LP + cc] =
                *(const uint4*)(Wsrc + (size_t)(j0 + r) * Kw + ks + cc);
        }
        __syncthreads();
#pragma unroll
        for (int kk = 0; kk < 64; kk += 32) {
            short8 a[2], b[2];
#pragma unroll
            for (int i = 0; i < 2; ++i)
                a[i] = *(const short8*)&As[(mBase + i * 16 + lrow) * LP + kk + lchunk];
#pragma unroll
            for (int j = 0; j < 2; ++j)
                b[j] = *(const short8*)&Bs[(nBase + j * 16 + lrow) * LP + kk + lchunk];
#pragma unroll
            for (int i = 0; i < 2; ++i)
#pragma unroll
                for (int j = 0; j < 2; ++j)
                    acc[i][j] = __builtin_amdgcn_mfma_f32_16x16x32_bf16(a[i], b[j], acc[i][j], 0, 0, 0);
        }
        __syncthreads();
    }

    // epilogue: C/D layout col=lane&15, row=(lane>>4)*4+reg
    const int lcol = lane & 15;
    const int lrow4 = (lane >> 4) * 4;
#pragma unroll
    for (int i = 0; i < 2; ++i) {
#pragma unroll
        for (int j = 0; j < 2; ++j) {
            int col = nBase + j * 16 + lcol;     // 0..63 within tile
            float bv = is_scalar ? bias[j0 + col] : 0.f;
#pragma unroll
            for (int r = 0; r < 4; ++r) {
                int row = row0 + mBase + i * 16 + lrow4 + r;
                if (row < N)
                    out[(size_t)row * 512 + outOff + j0 + col] = acc[i][j][r] + bv;
            }
        }
    }
}

extern "C" void kernel_launch(void* const* d_in, const int* in_sizes, int n_in,
                              void* d_out, int out_size, void* d_ws, size_t ws_size,
                              hipStream_t stream) {
    const float* x      = (const float*)d_in[0];
    const int*   ei     = (const int*)d_in[1];
    const float* Wsrel  = (const float*)d_in[2];
    const float* Wsroot = (const float*)d_in[3];
    const float* bs     = (const float*)d_in[4];
    const float* Wvrel  = (const float*)d_in[5];
    const float* Wvroot = (const float*)d_in[6];
    float* out = (float*)d_out;

    const int N  = in_sizes[0] / 512;
    const int E  = in_sizes[1] / 2;
    const int s2 = in_sizes[2];          // HIDDEN^2
    const int s5 = in_sizes[5];          // (3*HIDDEN)^2
    const int Nx = in_sizes[0];          // N*512
    const int Mt = (N + 63) / 64;

    // ws layout (~22 MB)
    char* ws = (char*)d_ws;
    size_t off = 0;
    int* counts = (int*)(ws + off);   off += (size_t)N * 4;        off = (off + 255) & ~(size_t)255;
    int* offsets = (int*)(ws + off);  off += (size_t)(N + 1) * 4;  off = (off + 255) & ~(size_t)255;
    int* cursor = (int*)(ws + off);   off += (size_t)N * 4;        off = (off + 255) & ~(size_t)255;
    int* edge_dst = (int*)(ws + off); off += (size_t)E * 4;        off = (off + 255) & ~(size_t)255;
    u16* Wb = (u16*)(ws + off);       off += (size_t)(2*s2 + 2*s5) * 2; off = (off + 255) & ~(size_t)255;
    u16* agg = (u16*)(ws + off);      off += (size_t)Nx * 2;       off = (off + 255) & ~(size_t)255;
    u16* x_bf = (u16*)(ws + off);

    const int n8   = Nx / 8;
    const int nw8  = (2 * s2 + 2 * s5) / 8;
    const int nb_x = (n8 + 255) / 256;
    const int nb_w = (nw8 + 255) / 256;
    const int nb_c = (E + 255) / 256;

    hipMemsetAsync(counts, 0, (size_t)N * 4, stream);
    prep_kernel<<<nb_x + nb_w + nb_c, 256, 0, stream>>>(
        x, x_bf, n8, Wsrel, Wsroot, Wvrel, Wvroot, Wb, s2, s5, nw8,
        ei, E, N, counts, nb_x, nb_w);
    scan_kernel<<<1, 1024, 0, stream>>>(counts, offsets, cursor, N);
    fill_kernel<<<(E + 255) / 256, 256, 0, stream>>>(ei, E, N, cursor, edge_dst);
    gather_kernel<<<(N * 64 + 255) / 256, 256, 0, stream>>>(x_bf, offsets, edge_dst, agg, N);
    dim3 grid(Mt, 8);
    gemm_kernel<<<grid, 256, 0, stream>>>(x_bf, agg, Wb, bs, s2, s5, out, N);
}

// Round 7
// 157.669 us; speedup vs baseline: 1.4080x; 1.0231x over previous
//
#include <hip/hip_runtime.h>
#include <stdint.h>

typedef unsigned short u16;
typedef unsigned int u32;
typedef __attribute__((ext_vector_type(4))) float floatx4;
typedef __attribute__((ext_vector_type(8))) short short8;

// Dtypes fixed: float32 tensors (R3 proof), int32 edge_index (R5 page-fault
// on int64 read + R3/R4 passing on the int32 path).

static __device__ __forceinline__ float bfhi2f(u32 hi) {
    union { u32 i; float f; } v; v.i = hi; return v.f;
}
static __device__ __forceinline__ u16 f2bf(float f) {
    union { float f; u32 i; } v; v.f = f;
    u32 r = v.i + 0x7fffu + ((v.i >> 16) & 1u);
    return (u16)(r >> 16);
}
static __device__ __forceinline__ uint4 pack8(const float* s) {
    float4 a = *(const float4*)s, b = *(const float4*)(s + 4);
    uint4 p;
    p.x = (u32)f2bf(a.x) | ((u32)f2bf(a.y) << 16);
    p.y = (u32)f2bf(a.z) | ((u32)f2bf(a.w) << 16);
    p.z = (u32)f2bf(b.x) | ((u32)f2bf(b.y) << 16);
    p.w = (u32)f2bf(b.z) | ((u32)f2bf(b.w) << 16);
    return p;
}

// ---------------- fused prep: x->bf16, W->bf16 (concat), edge count ----------------
// Wb layout: [Wsrel(s2) | Wsroot(s2) | Wvrel(s5) | Wvroot(s5)]

__global__ __launch_bounds__(256) void prep_kernel(
        const float* __restrict__ x, u16* __restrict__ xb, int n8,
        const float* __restrict__ w2, const float* __restrict__ w3,
        const float* __restrict__ w5, const float* __restrict__ w6,
        u16* __restrict__ Wb, int s2, int s5, int nw8,
        const int* __restrict__ ei, int E, int N, int* __restrict__ counts,
        int nb_x, int nb_w) {
    const int b = blockIdx.x, tid = threadIdx.x;
    if (b < nb_x) {
        int t = b * 256 + tid;
        if (t < n8) *(uint4*)(xb + (size_t)t * 8) = pack8(x + (size_t)t * 8);
    } else if (b < nb_x + nb_w) {
        int t = (b - nb_x) * 256 + tid;
        if (t < nw8) {
            int g = t * 8;
            const float* src; int loc;
            if (g < s2)               { src = w2; loc = g; }
            else if (g < 2 * s2)      { src = w3; loc = g - s2; }
            else if (g < 2 * s2 + s5) { src = w5; loc = g - 2 * s2; }
            else                      { src = w6; loc = g - 2 * s2 - s5; }
            *(uint4*)(Wb + g) = pack8(src + loc);
        }
    } else {
        int e = (b - nb_x - nb_w) * 256 + tid;
        if (e < E) {
            unsigned r = (unsigned)ei[e];
            unsigned c = (unsigned)ei[E + e];
            if (r < (unsigned)N && c < (unsigned)N) atomicAdd(&counts[r], 1);
        }
    }
}

// ---------------- single-block scan, 4 elems/thread (3 chunks for N=10000) ----------------

__global__ void scan_kernel(const int* __restrict__ counts, int* __restrict__ offsets,
                            int* __restrict__ cursor, int n) {
    __shared__ int part[16];
    __shared__ int carry;
    const int tid = threadIdx.x, lane = tid & 63, wave = tid >> 6;
    if (tid == 0) carry = 0;
    __syncthreads();
    for (int base = 0; base < n; base += 4096) {
        int i0 = base + tid * 4;
        int a0 = (i0     < n) ? counts[i0]     : 0;
        int a1 = (i0 + 1 < n) ? counts[i0 + 1] : 0;
        int a2 = (i0 + 2 < n) ? counts[i0 + 2] : 0;
        int a3 = (i0 + 3 < n) ? counts[i0 + 3] : 0;
        int s0 = a0, s1 = s0 + a1, s2 = s1 + a2, s3 = s2 + a3;
        int t = s3;                       // thread total
#pragma unroll
        for (int d = 1; d < 64; d <<= 1) {
            int q = __shfl_up(t, d);
            if (lane >= d) t += q;
        }
        if (lane == 63) part[wave] = t;   // wave-inclusive of thread totals
        __syncthreads();
        if (tid < 16) {
            int p = part[tid];
#pragma unroll
            for (int d = 1; d < 16; d <<= 1) {
                int q = __shfl_up(p, d);
                if (tid >= d) p += q;
            }
            part[tid] = p;
        }
        __syncthreads();
        int c0 = carry;
        int woff = wave ? part[wave - 1] : 0;
        int tbase = c0 + woff + (t - s3); // exclusive prefix of this thread's 1st elem
        if (i0     < n) { offsets[i0]     = tbase;      cursor[i0]     = tbase; }
        if (i0 + 1 < n) { offsets[i0 + 1] = tbase + s0; cursor[i0 + 1] = tbase + s0; }
        if (i0 + 2 < n) { offsets[i0 + 2] = tbase + s1; cursor[i0 + 2] = tbase + s1; }
        if (i0 + 3 < n) { offsets[i0 + 3] = tbase + s2; cursor[i0 + 3] = tbase + s2; }
        int tot = part[15];
        __syncthreads();
        if (tid == 0) carry = c0 + tot;
    }
    __syncthreads();
    if (tid == 0) offsets[n] = carry;
}

__global__ void fill_kernel(const int* __restrict__ ei, int E, int N,
                            int* __restrict__ cursor, int* __restrict__ edge_dst) {
    int e = blockIdx.x * blockDim.x + threadIdx.x;
    if (e >= E) return;
    unsigned r = (unsigned)ei[e];
    unsigned c = (unsigned)ei[E + e];
    if (r < (unsigned)N && c < (unsigned)N) {
        int p = atomicAdd(&cursor[r], 1);
        edge_dst[p] = (int)c;
    }
}

// ---------------- aggregate: agg[n,0:512] (bf16) = sum over in-edges ----------------
// One wave per node; 16-deep prefetch: one coalesced edge_dst load serves 16
// edges via __shfl broadcast, then 16 independent 1KB row loads in flight.

static __device__ __forceinline__ void acc8(float* acc, uint4 d) {
    acc[0] += bfhi2f(d.x << 16); acc[1] += bfhi2f(d.x & 0xffff0000u);
    acc[2] += bfhi2f(d.y << 16); acc[3] += bfhi2f(d.y & 0xffff0000u);
    acc[4] += bfhi2f(d.z << 16); acc[5] += bfhi2f(d.z & 0xffff0000u);
    acc[6] += bfhi2f(d.w << 16); acc[7] += bfhi2f(d.w & 0xffff0000u);
}

__global__ __launch_bounds__(256) void gather_kernel(
        const u16* __restrict__ xb, const int* __restrict__ offsets,
        const int* __restrict__ edge_dst, u16* __restrict__ agg, int N) {
    int gw   = (blockIdx.x * 256 + threadIdx.x) >> 6;
    int lane = threadIdx.x & 63;
    if (gw >= N) return;
    const int beg = offsets[gw], end = offsets[gw + 1];
    float acc[8] = {0.f,0.f,0.f,0.f,0.f,0.f,0.f,0.f};
    const u16* xl = xb + (size_t)lane * 8;   // lane's 16B column slot
    int e = beg;
    for (; e + 16 <= end; e += 16) {
        int myid = edge_dst[e + (lane & 15)];
        uint4 d[16];
#pragma unroll
        for (int u = 0; u < 16; ++u) {
            int c = __shfl(myid, u);
            d[u] = *(const uint4*)(xl + (size_t)c * 512);
        }
#pragma unroll
        for (int u = 0; u < 16; ++u) acc8(acc, d[u]);
    }
    if (e + 8 <= end) {
        int myid = edge_dst[e + (lane & 7)];
        uint4 d[8];
#pragma unroll
        for (int u = 0; u < 8; ++u) {
            int c = __shfl(myid, u);
            d[u] = *(const uint4*)(xl + (size_t)c * 512);
        }
#pragma unroll
        for (int u = 0; u < 8; ++u) acc8(acc, d[u]);
        e += 8;
    }
    if (e + 4 <= end) {
        int myid = edge_dst[e + (lane & 3)];
        uint4 d[4];
#pragma unroll
        for (int u = 0; u < 4; ++u) {
            int c = __shfl(myid, u);
            d[u] = *(const uint4*)(xl + (size_t)c * 512);
        }
#pragma unroll
        for (int u = 0; u < 4; ++u) acc8(acc, d[u]);
        e += 4;
    }
    for (; e < end; ++e) {
        int c = edge_dst[e];
        acc8(acc, *(const uint4*)(xl + (size_t)c * 512));
    }
    uint4 p;
    p.x = (u32)f2bf(acc[0]) | ((u32)f2bf(acc[1]) << 16);
    p.y = (u32)f2bf(acc[2]) | ((u32)f2bf(acc[3]) << 16);
    p.z = (u32)f2bf(acc[4]) | ((u32)f2bf(acc[5]) << 16);
    p.w = (u32)f2bf(acc[6]) | ((u32)f2bf(acc[7]) << 16);
    *(uint4*)(agg + (size_t)gw * 512 + (size_t)lane * 8) = p;
}

// ---------------- fused output GEMM (64x64 tiles, BK=128, grid Mt x 8) ----------------
// units 0-1: out[:, u*64+0..63]          = x_s@Ws_root^T + agg_s@Ws_rel^T + b
// units 2-7: out[:, 128+(u-2)*64+0..63]  = x_v@Wv_root^T + agg_v@Wv_rel^T
// BK=128: 32 MFMA per barrier (AITER ratio), K=768 -> 6 k-steps.

#define LP 136   // LDS pitch in bf16 elems (128 + 8 pad)

__global__ __launch_bounds__(256, 4) void gemm_kernel(
        const u16* __restrict__ xb, const u16* __restrict__ agg,
        const u16* __restrict__ Wb, const float* __restrict__ bias,
        int s2, int s5, float* __restrict__ out, int N) {
    const int unit = blockIdx.y;
    const bool is_scalar = (unit < 2);

    const int Kw      = is_scalar ? 128 : 384;
    const int K       = 2 * Kw;
    const int selfOff = is_scalar ? 0 : 128;
    const int j0      = is_scalar ? unit * 64 : (unit - 2) * 64;
    const int outOff  = is_scalar ? 0 : 128;
    const u16* Wrel   = is_scalar ? Wb : (Wb + 2 * s2);
    const u16* Wroot  = is_scalar ? (Wb + s2) : (Wb + 2 * s2 + s5);

    __shared__ u16 As[64 * LP];
    __shared__ u16 Bs[64 * LP];

    const int row0 = blockIdx.x * 64;
    const int tid  = threadIdx.x;
    const int lane = tid & 63, wid = tid >> 6;
    const int mBase = (wid >> 1) * 32, nBase = (wid & 1) * 32;
    const int lrow = lane & 15;
    const int lchunk = (lane >> 4) * 8;

    floatx4 acc[2][2];
#pragma unroll
    for (int i = 0; i < 2; ++i)
#pragma unroll
        for (int j = 0; j < 2; ++j) acc[i][j] = (floatx4){0.f, 0.f, 0.f, 0.f};

    for (int k0 = 0; k0 < K; k0 += 128) {
        const bool selfPhase = (k0 < Kw);
        const int ks   = selfPhase ? k0 : (k0 - Kw);
        const int acol = selfOff + ks;
        const u16* Asrc = selfPhase ? xb : agg;
        const u16* Wsrc = selfPhase ? Wroot : Wrel;
#pragma unroll
        for (int it = 0; it < 4; ++it) {
            int ci = it * 256 + tid;            // 0..1023 chunk index (64 rows x 16 chunks)
            int r = ci >> 4, cc = (ci & 15) << 3;
            int ar = row0 + r; if (ar >= N) ar = N - 1;
            *(uint4*)&As[r * LP + cc] =
                *(const uint4*)(Asrc + (size_t)ar * 512 + acol + cc);
            *(uint4*)&Bs[r * LP + cc] =
                *(const uint4*)(Wsrc + (size_t)(j0 + r) * Kw + ks + cc);
        }
        __syncthreads();
#pragma unroll
        for (int kk = 0; kk < 128; kk += 32) {
            short8 a[2], b[2];
#pragma unroll
            for (int i = 0; i < 2; ++i)
                a[i] = *(const short8*)&As[(mBase + i * 16 + lrow) * LP + kk + lchunk];
#pragma unroll
            for (int j = 0; j < 2; ++j)
                b[j] = *(const short8*)&Bs[(nBase + j * 16 + lrow) * LP + kk + lchunk];
#pragma unroll
            for (int i = 0; i < 2; ++i)
#pragma unroll
                for (int j = 0; j < 2; ++j)
                    acc[i][j] = __builtin_amdgcn_mfma_f32_16x16x32_bf16(a[i], b[j], acc[i][j], 0, 0, 0);
        }
        __syncthreads();
    }

    // epilogue: C/D layout col=lane&15, row=(lane>>4)*4+reg
    const int lcol = lane & 15;
    const int lrow4 = (lane >> 4) * 4;
#pragma unroll
    for (int i = 0; i < 2; ++i) {
#pragma unroll
        for (int j = 0; j < 2; ++j) {
            int col = nBase + j * 16 + lcol;     // 0..63 within tile
            float bv = is_scalar ? bias[j0 + col] : 0.f;
#pragma unroll
            for (int r = 0; r < 4; ++r) {
                int row = row0 + mBase + i * 16 + lrow4 + r;
                if (row < N)
                    out[(size_t)row * 512 + outOff + j0 + col] = acc[i][j][r] + bv;
            }
        }
    }
}

extern "C" void kernel_launch(void* const* d_in, const int* in_sizes, int n_in,
                              void* d_out, int out_size, void* d_ws, size_t ws_size,
                              hipStream_t stream) {
    const float* x      = (const float*)d_in[0];
    const int*   ei     = (const int*)d_in[1];
    const float* Wsrel  = (const float*)d_in[2];
    const float* Wsroot = (const float*)d_in[3];
    const float* bs     = (const float*)d_in[4];
    const float* Wvrel  = (const float*)d_in[5];
    const float* Wvroot = (const float*)d_in[6];
    float* out = (float*)d_out;

    const int N  = in_sizes[0] / 512;
    const int E  = in_sizes[1] / 2;
    const int s2 = in_sizes[2];          // HIDDEN^2
    const int s5 = in_sizes[5];          // (3*HIDDEN)^2
    const int Nx = in_sizes[0];          // N*512
    const int Mt = (N + 63) / 64;

    // ws layout (~22 MB)
    char* ws = (char*)d_ws;
    size_t off = 0;
    int* counts = (int*)(ws + off);   off += (size_t)N * 4;        off = (off + 255) & ~(size_t)255;
    int* offsets = (int*)(ws + off);  off += (size_t)(N + 1) * 4;  off = (off + 255) & ~(size_t)255;
    int* cursor = (int*)(ws + off);   off += (size_t)N * 4;        off = (off + 255) & ~(size_t)255;
    int* edge_dst = (int*)(ws + off); off += (size_t)E * 4;        off = (off + 255) & ~(size_t)255;
    u16* Wb = (u16*)(ws + off);       off += (size_t)(2*s2 + 2*s5) * 2; off = (off + 255) & ~(size_t)255;
    u16* agg = (u16*)(ws + off);      off += (size_t)Nx * 2;       off = (off + 255) & ~(size_t)255;
    u16* x_bf = (u16*)(ws + off);

    const int n8   = Nx / 8;
    const int nw8  = (2 * s2 + 2 * s5) / 8;
    const int nb_x = (n8 + 255) / 256;
    const int nb_w = (nw8 + 255) / 256;
    const int nb_c = (E + 255) / 256;

    hipMemsetAsync(counts, 0, (size_t)N * 4, stream);
    prep_kernel<<<nb_x + nb_w + nb_c, 256, 0, stream>>>(
        x, x_bf, n8, Wsrel, Wsroot, Wvrel, Wvroot, Wb, s2, s5, nw8,
        ei, E, N, counts, nb_x, nb_w);
    scan_kernel<<<1, 1024, 0, stream>>>(counts, offsets, cursor, N);
    fill_kernel<<<(E + 255) / 256, 256, 0, stream>>>(ei, E, N, cursor, edge_dst);
    gather_kernel<<<(N * 64 + 255) / 256, 256, 0, stream>>>(x_bf, offsets, edge_dst, agg, N);
    dim3 grid(Mt, 8);
    gemm_kernel<<<grid, 256, 0, stream>>>(x_bf, agg, Wb, bs, s2, s5, out, N);
}